// Round 9
// baseline (185.321 us; speedup 1.0000x reference)
//
#include <hip/hip_runtime.h>

typedef __bf16 bhalf;
typedef bhalf bhalf8 __attribute__((ext_vector_type(8)));
typedef float f32x4 __attribute__((ext_vector_type(4)));
typedef unsigned short u16;

__device__ __forceinline__ u16 f2bf(float f) {
  union { float f; unsigned u; } v; v.f = f;
  unsigned r = v.u + 0x7FFFu + ((v.u >> 16) & 1u);
  return (u16)(r >> 16);
}

// W0: [512][784] f32 -> bf16 [512][800] zero-pad; W1: [256][512]; W2: [10][256]->[16][256].
#define KP0 800
#define W0E (512 * KP0)
#define W1E (256 * 512)
#define W2E (16 * 256)

__global__ __launch_bounds__(256) void cvt_weights(
    const float* __restrict__ W0, const float* __restrict__ W1,
    const float* __restrict__ W2,
    u16* __restrict__ W0b, u16* __restrict__ W1b, u16* __restrict__ W2b)
{
  int i = blockIdx.x * 256 + threadIdx.x;
  if (i < W0E) {
    int r = i / KP0, k = i - r * KP0;
    W0b[i] = (k < 784) ? f2bf(W0[r * 784 + k]) : (u16)0;
    return;
  }
  i -= W0E;
  if (i < W1E) { W1b[i] = f2bf(W1[i]); return; }
  i -= W1E;
  if (i < W2E) {
    int r = i >> 8, c = i & 255;
    W2b[i] = (r < 10) ? f2bf(W2[r * 256 + c]) : (u16)0;
  }
}

// m1 = relu(x @ W0^T): 128x128 tile, 4 waves (2x2, wave 64x64), ZERO LDS, ZERO barriers.
// A fragments loaded f32 direct from x (cvt in reg); B fragments bf16 direct from W0b
// (L2-resident). 1-step prefetch both, unroll-2 ping-pong. 25 K-steps (K pad 800).
__global__ __launch_bounds__(256, 3) void gemm1_dd(
    const float* __restrict__ x, const u16* __restrict__ Wb, u16* __restrict__ Cp)
{
  const int t = threadIdx.x, w = t >> 6, lane = t & 63;
  const int bid = blockIdx.x;
  // XCD-aware: all 4 col-tiles of a row-tile on one XCD -> x panel + W0b L2-shared.
  const int rt = (bid & 7) + ((bid >> 5) << 3);
  const int ct = (bid >> 3) & 3;
  const size_t rbase = (size_t)rt * 128, cbase = (size_t)ct * 128;
  const int wr = w >> 1, wc = w & 1, fr = lane & 15, fg = lane >> 4;
  const int kb = fg * 8;

  const float* xR[4];
#pragma unroll
  for (int m = 0; m < 4; ++m)
    xR[m] = x + (rbase + wr * 64 + m * 16 + fr) * (size_t)784;
  const u16* bC[4];
#pragma unroll
  for (int n = 0; n < 4; ++n)
    bC[n] = Wb + (cbase + wc * 64 + n * 16 + fr) * (size_t)KP0 + kb;

  f32x4 acc[4][4];
#pragma unroll
  for (int m = 0; m < 4; ++m)
#pragma unroll
    for (int n = 0; n < 4; ++n) acc[m][n] = (f32x4){0.f, 0.f, 0.f, 0.f};

  f32x4 xn[4][2];
  bhalf8 xf[4], bfA[4], bfB[4];

#define LOADA(s) do { int kk = (s) * 32 + kb; if (kk >= 784) kk = 0;            \
    _Pragma("unroll") for (int m = 0; m < 4; ++m) {                             \
      const float* p = xR[m] + kk;                                              \
      xn[m][0] = *(const f32x4*)p; xn[m][1] = *(const f32x4*)(p + 4); } } while (0)
#define LOADB(s, dst) do { _Pragma("unroll") for (int n = 0; n < 4; ++n)        \
      dst[n] = *(const bhalf8*)(bC[n] + (s) * 32); } while (0)
#define CVT() do { _Pragma("unroll") for (int m = 0; m < 4; ++m) { bhalf8 v;    \
      _Pragma("unroll") for (int j = 0; j < 4; ++j) {                           \
        v[j] = (bhalf)xn[m][0][j]; v[4 + j] = (bhalf)xn[m][1][j]; }             \
      xf[m] = v; } } while (0)
#define MM(bf) do { __builtin_amdgcn_s_setprio(1);                              \
    _Pragma("unroll") for (int m = 0; m < 4; ++m)                               \
    _Pragma("unroll") for (int n = 0; n < 4; ++n)                               \
      acc[m][n] = __builtin_amdgcn_mfma_f32_16x16x32_bf16(xf[m], bf[n], acc[m][n], 0, 0, 0); \
    __builtin_amdgcn_s_setprio(0); } while (0)

  // prologue: step-0 operands in flight
  LOADA(0); LOADB(0, bfA);

  for (int i = 0; i < 12; ++i) {
    const int s = 2 * i;
    CVT();                          // xf = A(s): waits loads issued a full step ago
    LOADA(s + 1); LOADB(s + 1, bfB);
    MM(bfA);                        // step s
    CVT();                          // xf = A(s+1)
    LOADA(s + 2); LOADB(s + 2, bfA);
    MM(bfB);                        // step s+1
  }
  CVT();                            // xf = A(24)
  MM(bfA);                          // step 24

#undef LOADA
#undef LOADB
#undef CVT
#undef MM

  // epilogue: relu -> bf16, C/D layout col=lane&15, row=(lane>>4)*4+q
#pragma unroll
  for (int m = 0; m < 4; ++m)
#pragma unroll
    for (int n = 0; n < 4; ++n)
#pragma unroll
      for (int q = 0; q < 4; ++q) {
        size_t row = rbase + wr * 64 + m * 16 + fg * 4 + q;
        size_t col = cbase + wc * 64 + n * 16 + fr;
        float vv = acc[m][n][q];
        vv = vv > 0.f ? vv : 0.f;
        Cp[row * 512 + col] = f2bf(vv);
      }
}

// Fused layers 2+3: 64 rows x full 256 cols, 8 waves (2x4, wave 32x64), ZERO-LDS
// barrier-free main loop (A=m1 bf16 direct, B=W1b direct from L2); LDS only for the
// m2 relu tile + W2 in the layer-3 epilogue. 16 K-steps.
__global__ __launch_bounds__(512) void gemm23_dd(
    const u16* __restrict__ m1, const u16* __restrict__ W1b,
    const u16* __restrict__ W2b, float* __restrict__ out)
{
  __shared__ u16 m2s[64 * 264];
  __shared__ u16 W2s[16 * 264];
  const int t = threadIdx.x, w = t >> 6, lane = t & 63;
  const size_t rbase = (size_t)blockIdx.x * 64;
  const int wr = w >> 2, wc = w & 3, fr = lane & 15, fg = lane >> 4;
  const int kb = fg * 8;

  // stage W2 (16x256 = 512 int4 chunks; 512 threads)
  {
    int r = t >> 5, kc = (t & 31) * 8;
    *(int4*)&W2s[r * 264 + kc] = *(const int4*)(W2b + r * 256 + kc);
  }

  const u16* aR[2];
#pragma unroll
  for (int m = 0; m < 2; ++m)
    aR[m] = m1 + (rbase + wr * 32 + m * 16 + fr) * (size_t)512 + kb;
  const u16* bC[4];
#pragma unroll
  for (int n = 0; n < 4; ++n)
    bC[n] = W1b + (wc * 64 + n * 16 + fr) * (size_t)512 + kb;

  f32x4 acc[2][4];
#pragma unroll
  for (int m = 0; m < 2; ++m)
#pragma unroll
    for (int n = 0; n < 4; ++n) acc[m][n] = (f32x4){0.f, 0.f, 0.f, 0.f};

  bhalf8 afA[2], afB[2], bfA[4], bfB[4];

#define LDA(s, dst) do { _Pragma("unroll") for (int m = 0; m < 2; ++m)          \
      dst[m] = *(const bhalf8*)(aR[m] + (s) * 32); } while (0)
#define LDB(s, dst) do { _Pragma("unroll") for (int n = 0; n < 4; ++n)          \
      dst[n] = *(const bhalf8*)(bC[n] + (s) * 32); } while (0)
#define MM2(af, bf) do { __builtin_amdgcn_s_setprio(1);                         \
    _Pragma("unroll") for (int m = 0; m < 2; ++m)                               \
    _Pragma("unroll") for (int n = 0; n < 4; ++n)                               \
      acc[m][n] = __builtin_amdgcn_mfma_f32_16x16x32_bf16(af[m], bf[n], acc[m][n], 0, 0, 0); \
    __builtin_amdgcn_s_setprio(0); } while (0)

  LDA(0, afA); LDB(0, bfA);
  for (int i = 0; i < 8; ++i) {
    const int s = 2 * i;
    LDA(s + 1, afB); LDB(s + 1, bfB);
    MM2(afA, bfA);                  // step s
    if (i < 7) { LDA(s + 2, afA); LDB(s + 2, bfA); }
    MM2(afB, bfB);                  // step s+1
  }

#undef LDA
#undef LDB
#undef MM2

  // m2 = relu(acc) -> bf16 tile in LDS
#pragma unroll
  for (int m = 0; m < 2; ++m)
#pragma unroll
    for (int n = 0; n < 4; ++n)
#pragma unroll
      for (int q = 0; q < 4; ++q) {
        int row = wr * 32 + m * 16 + fg * 4 + q;
        int col = wc * 64 + n * 16 + fr;
        float vv = acc[m][n][q];
        vv = vv > 0.f ? vv : 0.f;
        m2s[row * 264 + col] = f2bf(vv);
      }
  __syncthreads();

  // layer 3: waves 0-3 handle rows w*16..w*16+15; K=256 (8 ksubs)
  if (w < 4) {
    f32x4 acc3 = (f32x4){0.f, 0.f, 0.f, 0.f};
    const int arow = w * 16 + fr;
#pragma unroll
    for (int ks = 0; ks < 8; ++ks) {
      bhalf8 a = *(const bhalf8*)&m2s[arow * 264 + ks * 32 + kb];
      bhalf8 b = *(const bhalf8*)&W2s[fr * 264 + ks * 32 + kb];
      acc3 = __builtin_amdgcn_mfma_f32_16x16x32_bf16(a, b, acc3, 0, 0, 0);
    }
    if (fr < 10) {
#pragma unroll
      for (int q = 0; q < 4; ++q) {
        size_t row = rbase + w * 16 + fg * 4 + q;
        float vv = acc3[q];
        out[row * 10 + fr] = vv > 0.f ? vv : 0.f;
      }
    }
  }
}

extern "C" void kernel_launch(void* const* d_in, const int* in_sizes, int n_in,
                              void* d_out, int out_size, void* d_ws, size_t ws_size,
                              hipStream_t stream) {
  const float* x  = (const float*)d_in[0];
  const float* W0 = (const float*)d_in[1];
  const float* W1 = (const float*)d_in[2];
  const float* W2 = (const float*)d_in[3];
  float* out = (float*)d_out;

  char* ws = (char*)d_ws;
  u16* m1  = (u16*)(ws);                    // 32768x512 bf16 = 33554432 B
  u16* W0b = (u16*)(ws + 33554432);         // 512x800 = 819200 B
  u16* W1b = (u16*)(ws + 34373632);         // 256x512 = 262144 B
  u16* W2b = (u16*)(ws + 34635776);         // 16x256  = 8192 B

  cvt_weights<<<dim3((W0E + W1E + W2E + 255) / 256), dim3(256), 0, stream>>>(
      W0, W1, W2, W0b, W1b, W2b);

  // m1 = relu(x @ W0^T): 256 row-tiles x 4 col-tiles, barrier-free direct-operand GEMM
  gemm1_dd<<<dim3(1024), dim3(256), 0, stream>>>(x, W0b, m1);

  // out = relu(relu(m1 @ W1^T) @ W2^T): fused, barrier-free main loop
  gemm23_dd<<<dim3(512), dim3(512), 0, stream>>>(m1, W1b, W2b, out);
}

// Round 10
// 62.263 us; speedup vs baseline: 2.9764x; 2.9764x over previous
//
#include <hip/hip_runtime.h>

typedef __bf16 bhalf;
typedef bhalf bhalf8 __attribute__((ext_vector_type(8)));
typedef float f32x4 __attribute__((ext_vector_type(4)));
typedef unsigned short u16;
typedef u16 u16x8 __attribute__((ext_vector_type(8)));

__device__ __forceinline__ u16 f2bf(float f) {
  union { float f; unsigned u; } v; v.f = f;
  unsigned r = v.u + 0x7FFFu + ((v.u >> 16) & 1u);
  return (u16)(r >> 16);
}

// XOR swizzle keyed on bits 7-9; involution; <=2-way banks on frag reads.
__device__ __forceinline__ int swz(int L) { return L ^ (((L >> 7) & 7) << 4); }

#define GLL16(gp, lp) __builtin_amdgcn_global_load_lds( \
    (const __attribute__((address_space(1))) unsigned int*)(gp), \
    (__attribute__((address_space(3))) unsigned int*)(lp), 16, 0, 0)

// W0: [512][784] f32 -> bf16 [512][800] zero-pad; W1: [256][512]; W2: [10][256]->[16][256].
#define KP0 800
#define W0E (512 * KP0)
#define W1E (256 * 512)
#define W2E (16 * 256)

__global__ __launch_bounds__(256) void cvt_weights(
    const float* __restrict__ W0, const float* __restrict__ W1,
    const float* __restrict__ W2,
    u16* __restrict__ W0b, u16* __restrict__ W1b, u16* __restrict__ W2b)
{
  int i = blockIdx.x * 256 + threadIdx.x;
  if (i < W0E) {
    int r = i / KP0, k = i - r * KP0;
    W0b[i] = (k < 784) ? f2bf(W0[r * 784 + k]) : (u16)0;
    return;
  }
  i -= W0E;
  if (i < W1E) { W1b[i] = f2bf(W1[i]); return; }
  i -= W1E;
  if (i < W2E) {
    int r = i >> 8, c = i & 255;
    W2b[i] = (r < 10) ? f2bf(W2[r * 256 + c]) : (u16)0;
  }
}

// m1 = relu(x @ W0^T): 256x256 tile, BK=32, 8 waves (2Mx4N, wave 128x64), dbuf 64KB,
// two-barrier K-step, counted vmcnt(6), compiler-scheduled lgkm waits (no mid-phase
// drains), T2 swizzle, T5 setprio, T1 XCD map. 25 K-tiles (K pad 800).
__global__ __launch_bounds__(512) void gemm1_8p(
    const float* __restrict__ x, const u16* __restrict__ Wb, u16* __restrict__ Cp)
{
  __shared__ u16 lds[32768];    // bytes: A0 @0, A1 @16384, B0 @32768, B1 @49152
  const int t = threadIdx.x, w = t >> 6, lane = t & 63;
  const int bid = blockIdx.x;
  // XCD x = bid%8 owns rt x*16..x*16+15 -> x-panel L2-shared within XCD.
  const int rt = (bid & 7) * 16 + (bid >> 4);
  const int ct = (bid >> 3) & 1;
  const size_t rbase = (size_t)rt * 256, cbase = (size_t)ct * 256;
  const int wr = w >> 2, wc = w & 3, fr = lane & 15, fg = lane >> 4;

  int aO[4], bO[4];
#pragma unroll
  for (int m = 0; m < 4; ++m) aO[m] = swz((wr * 128 + m * 16 + fr) * 64 + fg * 16);
#pragma unroll
  for (int n = 0; n < 4; ++n) bO[n] = swz((wc * 64 + n * 16 + fr) * 64 + fg * 16);

  // B staging: 2 gll/wave; source pre-swizzled
  const u16* bSrc[2];
#pragma unroll
  for (int i = 0; i < 2; ++i) {
    int P = (w * 2 + i) * 1024 + lane * 16;
    int U = swz(P);
    bSrc[i] = Wb + (size_t)(cbase + (U >> 6)) * KP0 + ((U & 63) >> 1);
  }

  // A staging: 2 chunks/thread (16B bf16 dest = 8 f32 src each)
  const float* xRow[2]; int aKe[2];
#pragma unroll
  for (int c2 = 0; c2 < 2; ++c2) {
    int P = c2 * 8192 + t * 16;
    int U = swz(P);
    xRow[c2] = x + (size_t)(rbase + (U >> 6)) * 784;
    aKe[c2] = (U & 63) >> 1;
  }

  f32x4 acc[8][4];
#pragma unroll
  for (int m = 0; m < 8; ++m)
#pragma unroll
    for (int n = 0; n < 4; ++n) acc[m][n] = (f32x4){0.f, 0.f, 0.f, 0.f};

  f32x4 xr[2][2];
  bhalf8 bf[4], afA[4], afB[4];

  auto loadX = [&](int ttn) {
#pragma unroll
    for (int c2 = 0; c2 < 2; ++c2) {
      int gk = ttn * 32 + aKe[c2];
      const float* p = xRow[c2] + ((gk < 784) ? gk : 0);  // clamp: W0b zero-padded
      xr[c2][0] = *(const f32x4*)p; xr[c2][1] = *(const f32x4*)(p + 4);
    }
  };
  auto cvtW = [&](int aBaseOther) {
#pragma unroll
    for (int c2 = 0; c2 < 2; ++c2) {
      u16x8 v;
#pragma unroll
      for (int j = 0; j < 4; ++j) { v[j] = f2bf(xr[c2][0][j]); v[4 + j] = f2bf(xr[c2][1][j]); }
      *(u16x8*)((char*)lds + aBaseOther + c2 * 8192 + t * 16) = v;
    }
  };
  auto stageB = [&](int ttn, int bBaseT) {
#pragma unroll
    for (int i = 0; i < 2; ++i)
      GLL16(bSrc[i] + ttn * 32, (char*)lds + bBaseT + (w * 2 + i) * 1024);
  };
  auto rdB  = [&](int bB) {
#pragma unroll
    for (int n = 0; n < 4; ++n) bf[n] = *(const bhalf8*)((const char*)lds + bB + bO[n]);
  };
  auto rdA0 = [&](int aB) {
#pragma unroll
    for (int m = 0; m < 4; ++m) afA[m] = *(const bhalf8*)((const char*)lds + aB + aO[m]);
  };
  auto rdA1 = [&](int aB) {
#pragma unroll
    for (int m = 0; m < 4; ++m) afB[m] = *(const bhalf8*)((const char*)lds + aB + aO[m] + 4096);
  };
  auto mfmaLo = [&]() {
    __builtin_amdgcn_s_setprio(1);
#pragma unroll
    for (int m = 0; m < 4; ++m)
#pragma unroll
      for (int n = 0; n < 4; ++n)
        acc[m][n] = __builtin_amdgcn_mfma_f32_16x16x32_bf16(afA[m], bf[n], acc[m][n], 0, 0, 0);
    __builtin_amdgcn_s_setprio(0);
  };
  auto mfmaHi = [&]() {
    __builtin_amdgcn_s_setprio(1);
#pragma unroll
    for (int m = 0; m < 4; ++m)
#pragma unroll
      for (int n = 0; n < 4; ++n)
        acc[4 + m][n] = __builtin_amdgcn_mfma_f32_16x16x32_bf16(afB[m], bf[n], acc[4 + m][n], 0, 0, 0);
    __builtin_amdgcn_s_setprio(0);
  };

  // ---- prologue: tile0 staged, tile1 in flight ----
  loadX(0);
  stageB(0, 32768);
  cvtW(0);            // auto-waits x(0); gll(0) keeps flying
  loadX(1);
  stageB(1, 49152);
  asm volatile("s_waitcnt vmcnt(6) lgkmcnt(0)" ::: "memory");  // B(0) landed, A0 written
  __builtin_amdgcn_s_barrier();

  // ---- steady loop: tiles 0..22 ----
  for (int tt = 0; tt < 23; ++tt) {
    const int c = tt & 1;
    const int aB = c << 14;             // A[c]
    const int bB = 32768 + (c << 14);   // B[c]
    // phase A: issue all 12 frag reads; compiler fine-grains the lgkm waits
    rdB(bB); rdA0(aB); rdA1(aB);
    mfmaLo();
    asm volatile("s_waitcnt lgkmcnt(0)" ::: "memory");  // all reads of buf[c] done
    __builtin_amdgcn_s_barrier();
    // phase B: stage tt+1's A (regs->LDS), issue tt+2, overlap with mfmaHi
    cvtW(aB ^ 16384);                   // A(tt+1) -> other A buf (auto-waits x(tt+1))
    loadX(tt + 2);                      // x(tt+2) into freed regs
    stageB(tt + 2, bB);                 // B(tt+2) -> just-freed B[c]
    mfmaHi();
    asm volatile("s_waitcnt vmcnt(6) lgkmcnt(0)" ::: "memory");  // B(tt+1) landed
    __builtin_amdgcn_s_barrier();
  }
  // ---- tail: tt=23 (no prefetch), tt=24 (last) ----
  {
    rdB(49152); rdA0(16384); rdA1(16384);   // tile 23 in buf1
    mfmaLo();
    asm volatile("s_waitcnt lgkmcnt(0)" ::: "memory");
    __builtin_amdgcn_s_barrier();
    cvtW(0);                                // A(24) -> buf0
    mfmaHi();
    asm volatile("s_waitcnt vmcnt(0) lgkmcnt(0)" ::: "memory");  // drain B(24)
    __builtin_amdgcn_s_barrier();

    rdB(32768); rdA0(0); rdA1(0);           // tile 24 in buf0
    mfmaLo();
    rdA1(0);
    mfmaHi();
  }

  // epilogue: relu -> bf16
#pragma unroll
  for (int m = 0; m < 8; ++m)
#pragma unroll
    for (int n = 0; n < 4; ++n)
#pragma unroll
      for (int q = 0; q < 4; ++q) {
        size_t row = rbase + wr * 128 + m * 16 + fg * 4 + q;
        size_t col = cbase + wc * 64 + n * 16 + fr;
        float vv = acc[m][n][q];
        vv = vv > 0.f ? vv : 0.f;
        Cp[row * 512 + col] = f2bf(vv);
      }
}

// Fused layers 2+3 (r5/r8 proven version): 64 rows x full 256 cols, 8 waves (2x4),
// BK=32, 16 steps, all-GLL dbuf, 2 blocks/CU.
__global__ __launch_bounds__(512, 4) void gemm23(
    const u16* __restrict__ m1, const u16* __restrict__ W1b,
    const u16* __restrict__ W2b, float* __restrict__ out)
{
  __shared__ u16 pool[20480];
  __shared__ u16 W2s[16][264];
  const int t = threadIdx.x, w = t >> 6, lane = t & 63;
  const size_t rbase = (size_t)blockIdx.x * 64;
  const int wr = w >> 2, wc = w & 3, fr = lane & 15, fg = lane >> 4;

  {
    int r = t >> 5, kc = (t & 31) * 8;
    *(int4*)&W2s[r][kc] = *(const int4*)(W2b + r * 256 + kc);
  }

  int aOff[2], bOff[4];
#pragma unroll
  for (int i = 0; i < 2; ++i) aOff[i] = swz((wr * 32 + i * 16 + fr) * 64 + fg * 16);
#pragma unroll
  for (int j = 0; j < 4; ++j) bOff[j] = swz((wc * 64 + j * 16 + fr) * 64 + fg * 16);

  const u16* aSrc = nullptr; int aDst = 0;
  if (w < 4) {
    int Dl = (w * 64 + lane) * 16;
    int Ul = swz(Dl);
    aSrc = m1 + (rbase + (Ul >> 6)) * 512 + ((Ul & 63) >> 1);
    aDst = (w * 64) * 16;
  }
  const u16* bSrc[2]; int bDst[2];
#pragma unroll
  for (int i = 0; i < 2; ++i) {
    int Dl = (w * 128 + i * 64 + lane) * 16;
    int Ul = swz(Dl);
    bSrc[i] = W1b + (Ul >> 6) * 512 + ((Ul & 63) >> 1);
    bDst[i] = 8192 + (w * 128 + i * 64) * 16;
  }

  f32x4 acc[2][4];
#pragma unroll
  for (int i = 0; i < 2; ++i)
#pragma unroll
    for (int j = 0; j < 4; ++j) acc[i][j] = (f32x4){0.f, 0.f, 0.f, 0.f};

  if (w < 4) GLL16(aSrc, (char*)pool + aDst);
#pragma unroll
  for (int i = 0; i < 2; ++i) GLL16(bSrc[i], (char*)pool + bDst[i]);

  for (int tt = 0; tt < 16; ++tt) {
    const int cur = tt & 1;
    const char* Asc = (const char*)pool + cur * 4096;
    const char* Bsc = (const char*)pool + 8192 + cur * 16384;
    asm volatile("s_waitcnt vmcnt(0)" ::: "memory");
    __syncthreads();

    if (tt < 15) {
      const int k0 = (tt + 1) * 32;
      if (w < 4) GLL16(aSrc + k0, (char*)pool + (cur ^ 1) * 4096 + aDst);
#pragma unroll
      for (int i = 0; i < 2; ++i)
        GLL16(bSrc[i] + k0, (char*)pool + (cur ^ 1) * 16384 + bDst[i]);
    }

    bhalf8 af[2], bfv[4];
#pragma unroll
    for (int i = 0; i < 2; ++i) af[i] = *(const bhalf8*)(Asc + aOff[i]);
#pragma unroll
    for (int j = 0; j < 4; ++j) bfv[j] = *(const bhalf8*)(Bsc + bOff[j]);
#pragma unroll
    for (int i = 0; i < 2; ++i)
#pragma unroll
      for (int j = 0; j < 4; ++j)
        acc[i][j] = __builtin_amdgcn_mfma_f32_16x16x32_bf16(af[i], bfv[j], acc[i][j], 0, 0, 0);
  }

  __syncthreads();
#pragma unroll
  for (int i = 0; i < 2; ++i)
#pragma unroll
    for (int j = 0; j < 4; ++j)
#pragma unroll
      for (int q = 0; q < 4; ++q) {
        int row = wr * 32 + i * 16 + fg * 4 + q;
        int col = wc * 64 + j * 16 + fr;
        float vv = acc[i][j][q];
        vv = vv > 0.f ? vv : 0.f;
        pool[row * 264 + col] = f2bf(vv);
      }
  __syncthreads();

  if (w < 4) {
    f32x4 acc3 = (f32x4){0.f, 0.f, 0.f, 0.f};
    const int arow = w * 16 + fr;
#pragma unroll
    for (int ks = 0; ks < 8; ++ks) {
      bhalf8 a = *(const bhalf8*)&pool[arow * 264 + ks * 32 + fg * 8];
      bhalf8 b = *(const bhalf8*)&W2s[fr][ks * 32 + fg * 8];
      acc3 = __builtin_amdgcn_mfma_f32_16x16x32_bf16(a, b, acc3, 0, 0, 0);
    }
    if (fr < 10) {
#pragma unroll
      for (int q = 0; q < 4; ++q) {
        size_t row = rbase + w * 16 + fg * 4 + q;
        float vv = acc3[q];
        out[row * 10 + fr] = vv > 0.f ? vv : 0.f;
      }
    }
  }
}

extern "C" void kernel_launch(void* const* d_in, const int* in_sizes, int n_in,
                              void* d_out, int out_size, void* d_ws, size_t ws_size,
                              hipStream_t stream) {
  const float* x  = (const float*)d_in[0];
  const float* W0 = (const float*)d_in[1];
  const float* W1 = (const float*)d_in[2];
  const float* W2 = (const float*)d_in[3];
  float* out = (float*)d_out;

  char* ws = (char*)d_ws;
  u16* m1  = (u16*)(ws);                    // 32768x512 bf16 = 33554432 B
  u16* W0b = (u16*)(ws + 33554432);         // 512x800 = 819200 B
  u16* W1b = (u16*)(ws + 34373632);         // 256x512 = 262144 B
  u16* W2b = (u16*)(ws + 34635776);         // 16x256  = 8192 B

  cvt_weights<<<dim3((W0E + W1E + W2E + 255) / 256), dim3(256), 0, stream>>>(
      W0, W1, W2, W0b, W1b, W2b);

  // m1 = relu(x @ W0^T): 128 row-tiles x 2 col-tiles = 256 blocks, 1/CU
  gemm1_8p<<<dim3(256), dim3(512), 0, stream>>>(x, W0b, m1);

  // out = relu(relu(m1 @ W1^T) @ W2^T)
  gemm23<<<dim3(512), dim3(512), 0, stream>>>(m1, W1b, W2b, out);
}